// Round 13
// baseline (700.462 us; speedup 1.0000x reference)
//
#include <hip/hip_runtime.h>
#include <cstdint>

// ---------------------------------------------------------------------------
// SimpleGAT: 3x (GATv2 -> GraphNorm -> ReLU) -> mean pool -> linear
// N=50000, E=800000 (+N self loops), H=4 heads, D=64/32/16, G=32 graphs
// Round 13: dispatch-count 19 -> 13 via safe last-block finalization
// (one counter bump/block; NOT R11's per-feature atomic hotspot):
//   - gn_final folded into gn_stats (last block computes sc/sh)      [-3]
//   - finalize folded into norm_pool (last block)                    [-1]
//   - chunk_sums folded into scan (each block sums its own prefix)   [-1]
//   - wprep merged with deg/batch hist (disjoint block ranges)       [-1]
// Heavy kernels (gemm duals, gat_fused) unchanged from R12.
// ---------------------------------------------------------------------------

#define NEG_SLOPE 0.2f

typedef __attribute__((ext_vector_type(8))) short short8;
typedef __attribute__((ext_vector_type(4))) float f32x4;
typedef _Float16 h2 __attribute__((ext_vector_type(2)));
union U16 { uint4 u; short8 s; };

__device__ inline unsigned short f2bf_rne(float x) {
  unsigned u = __float_as_uint(x);
  return (unsigned short)((u + 0x7fff + ((u >> 16) & 1)) >> 16);
}
__device__ inline unsigned short f2h_bits(float x) {
  _Float16 h = (_Float16)x;
  return __builtin_bit_cast(unsigned short, h);
}
__device__ inline float h2f(unsigned short h) {
  return (float)__builtin_bit_cast(_Float16, h);
}
__device__ inline h2 u2h2(unsigned u) { return __builtin_bit_cast(h2, u); }

__device__ inline float fdot2h(h2 a, h2 b, float c) {
#if __has_builtin(__builtin_amdgcn_fdot2)
  return __builtin_amdgcn_fdot2(a, b, c, false);
#else
  return c + (float)a.x * (float)b.x + (float)a.y * (float)b.y;
#endif
}

__device__ inline int wave_incl_scan(int v, int lane) {
#pragma unroll
  for (int ofs = 1; ofs < 64; ofs <<= 1) {
    int t = __shfl_up(v, ofs, 64);
    if (lane >= ofs) v += t;
  }
  return v;
}

// ---------------- weight pre-pack body --------------------------------------
__device__ inline void wprep_body(const float* __restrict__ W, unsigned short* __restrict__ pk,
                                  int K, int M, int t) {
  int nk = K >> 5;
  int total = (M >> 4) * nk * 512;
  if (t >= total) return;
  int j = t & 7;
  int l = (t >> 3) & 63;
  int rest = t >> 9;
  int kc = rest % nk;
  int ct = rest / nk;
  int k = (kc << 5) + ((l >> 4) << 3) + j;
  int col = (ct << 4) + (l & 15);
  float w = W[(size_t)k * M + col];
  unsigned u = __float_as_uint(w);
  unsigned short hi = (unsigned short)(u >> 16);
  float hif = __uint_as_float(u & 0xffff0000u);
  unsigned short lo = f2bf_rne(w - hif);
  unsigned short* dst = pk + ((size_t)(ct * nk + kc) * 64 + l) * 16;
  dst[j] = hi;
  dst[j + 8] = lo;
}

// ---- merged: deg/batch hist (blocks < HB) + weight pre-pack (blocks >= HB) --
__global__ void prep_hist(const int* __restrict__ ei, const int* __restrict__ batch,
                          int* __restrict__ deg, int* __restrict__ cnt, int E, int N, int HB,
                          const float* W0, const float* W1, const float* W2,
                          const float* W3, const float* W4, const float* W5,
                          unsigned short* p0, unsigned short* p1, unsigned short* p2,
                          unsigned short* p3, unsigned short* p4, unsigned short* p5) {
  __shared__ int h[32];
  int b = blockIdx.x;
  if (b < HB) {
    if (threadIdx.x < 32) h[threadIdx.x] = 0;
    __syncthreads();
    int i = b * 256 + threadIdx.x;
    int ET = E + N;
    if (i < ET) {
      int d = (i < E) ? ei[E + i] : (i - E);
      atomicAdd(&deg[d], 1);
    }
    if (i < N) atomicAdd(&h[batch[i]], 1);
    __syncthreads();
    if (threadIdx.x < 32 && h[threadIdx.x] > 0) atomicAdd(&cnt[threadIdx.x], h[threadIdx.x]);
  } else {
    int idx = b - HB;
    int m = idx >> 7;                       // matrix id (128 blocks each)
    int t = (idx & 127) * 256 + threadIdx.x;
    switch (m) {
      case 0: wprep_body(W0, p0, 128, 256, t); break;
      case 1: wprep_body(W1, p1, 128, 256, t); break;
      case 2: wprep_body(W2, p2, 256, 128, t); break;
      case 3: wprep_body(W3, p3, 256, 128, t); break;
      case 4: wprep_body(W4, p4, 128, 64, t); break;
      default: wprep_body(W5, p5, 128, 64, t); break;
    }
  }
}

// ---- single-kernel exclusive scan: each block sums its own prefix region ----
// (prefix reads <=48K ints, deg is 200KB L2-resident -> trivial; no
//  inter-block communication, no ordering assumptions)
__global__ void scan_all(const int* __restrict__ deg, int* __restrict__ off, int n) {
  __shared__ int ws[16];
  __shared__ int red[16];
  int tid = threadIdx.x, lane = tid & 63, wid = tid >> 6;
  // boff = sum(deg[0 .. blockIdx*1024))
  int pend = blockIdx.x * 1024;
  int part = 0;
  for (int i = tid; i < pend; i += 1024) part += deg[i];
#pragma unroll
  for (int m = 32; m; m >>= 1) part += __shfl_xor(part, m, 64);
  if (lane == 0) red[wid] = part;
  __syncthreads();
  if (tid == 0) {
    int s = 0;
#pragma unroll
    for (int k = 0; k < 16; ++k) s += red[k];
    red[0] = s;
  }
  __syncthreads();
  int boff = red[0];
  // local scan of this block's chunk
  int i = blockIdx.x * 1024 + tid;
  int v = (i < n) ? deg[i] : 0;
  int incl = wave_incl_scan(v, lane);
  if (lane == 63) ws[wid] = incl;
  __syncthreads();
  if (wid == 0) {
    int t = (lane < 16) ? ws[lane] : 0;
    t = wave_incl_scan(t, lane);
    if (lane < 16) ws[lane] = t;
  }
  __syncthreads();
  int wpre = (wid > 0) ? ws[wid - 1] : 0;
  if (i < n) off[i] = boff + wpre + incl - v;
  if (blockIdx.x == gridDim.x - 1 && tid == 0) off[n] = boff + ws[15];
}

__global__ void scatter_edges(const int* __restrict__ ei, const int* __restrict__ off,
                              int* __restrict__ cur, int* __restrict__ csr_src,
                              int E, int N) {
  int i = blockIdx.x * blockDim.x + threadIdx.x;
  int ET = E + N;
  if (i >= ET) return;
  int s, d;
  if (i < E) { s = ei[i]; d = ei[E + i]; } else { s = d = i - E; }
  int pos = off[d] + atomicAdd(&cur[d], 1);
  csr_src[pos] = s;
}

// ---- shared LDS-bounce epilogue: acc tiles -> coalesced fp16 row stores ----
__device__ inline void gemm_epilogue(
    unsigned short* __restrict__ sb0, unsigned short* __restrict__ sb1,
    f32x4* accL, f32x4* accR,
    const float* __restrict__ biasL, const float* __restrict__ biasR,
    unsigned short* __restrict__ CL, unsigned short* __restrict__ CR,
    int N, int M, int c0g, int row0blk) {
  int wv = threadIdx.x >> 6, lane = threadIdx.x & 63;
  int lrow0 = wv * 16 + ((lane >> 4) << 2);
  int lcolb = lane & 15;
#pragma unroll
  for (int ct = 0; ct < 4; ++ct) {
    int lcol = (ct << 4) + lcolb;
    float bvL = biasL[(c0g << 4) + lcol];
    float bvR = biasR[(c0g << 4) + lcol];
#pragma unroll
    for (int r = 0; r < 4; ++r) {
      sb0[(lrow0 + r) * 72 + lcol] = f2h_bits(accL[ct][r] + bvL);
      sb1[(lrow0 + r) * 72 + lcol] = f2h_bits(accR[ct][r] + bvR);
    }
  }
  __syncthreads();
  int tid = threadIdx.x;
#pragma unroll
  for (int pass = 0; pass < 2; ++pass) {
    int row = (tid >> 3) + (pass << 5);
    int gr = row0blk + row;
    if (gr < N) {
      int co = (tid & 7) << 3;
      uint4 vL = *(const uint4*)&sb0[row * 72 + co];
      uint4 vR = *(const uint4*)&sb1[row * 72 + co];
      size_t go = (size_t)gr * M + (c0g << 4) + co;
      *(uint4*)(CL + go) = vL;
      *(uint4*)(CR + go) = vR;
    }
  }
}

// ---------------- dual MFMA GEMM (fp32 A, hi/lo split ONCE, fp16 out x2) ----
template <int K, int M>
__global__ __launch_bounds__(256) void gemm_f32a_dual(
    const float* __restrict__ A,
    const uint4* __restrict__ WpkL, const uint4* __restrict__ WpkR,
    const float* __restrict__ biasL, const float* __restrict__ biasR,
    unsigned short* __restrict__ CL, unsigned short* __restrict__ CR, int N) {
  constexpr int nk = K >> 5;
  __shared__ unsigned short sb[2][64 * 72];
  int wv = threadIdx.x >> 6, lane = threadIdx.x & 63;
  int r0 = blockIdx.y * 64 + wv * 16;
  int c0g = blockIdx.x << 2;
  int row = r0 + (lane & 15);
  int kq = (lane >> 4) << 3;
  bool rok = row < N;
  const float* arow = A + (size_t)row * K;
  f32x4 accL[4], accR[4];
#pragma unroll
  for (int i = 0; i < 4; ++i) { accL[i] = (f32x4){0,0,0,0}; accR[i] = (f32x4){0,0,0,0}; }
#pragma unroll
  for (int kc = 0; kc < nk; ++kc) {
    float av[8];
    if (rok) {
      float4 t0 = *(const float4*)(arow + (kc << 5) + kq);
      float4 t1 = *(const float4*)(arow + (kc << 5) + kq + 4);
      av[0] = t0.x; av[1] = t0.y; av[2] = t0.z; av[3] = t0.w;
      av[4] = t1.x; av[5] = t1.y; av[6] = t1.z; av[7] = t1.w;
    } else {
#pragma unroll
      for (int j = 0; j < 8; ++j) av[j] = 0.f;
    }
    short8 ahi, alo;
#pragma unroll
    for (int j = 0; j < 8; ++j) {
      unsigned u = __float_as_uint(av[j]);
      ahi[j] = (short)(u >> 16);
      float hif = __uint_as_float(u & 0xffff0000u);
      alo[j] = (short)f2bf_rne(av[j] - hif);
    }
#pragma unroll
    for (int ct = 0; ct < 4; ++ct) {
      size_t fo = (((size_t)(c0g + ct) * nk + kc) * 64 + lane) * 2;
      U16 bh, bl;
      bh.u = WpkL[fo]; bl.u = WpkL[fo + 1];
      accL[ct] = __builtin_amdgcn_mfma_f32_16x16x32_bf16(alo, bh.s, accL[ct], 0, 0, 0);
      accL[ct] = __builtin_amdgcn_mfma_f32_16x16x32_bf16(ahi, bl.s, accL[ct], 0, 0, 0);
      accL[ct] = __builtin_amdgcn_mfma_f32_16x16x32_bf16(ahi, bh.s, accL[ct], 0, 0, 0);
      bh.u = WpkR[fo]; bl.u = WpkR[fo + 1];
      accR[ct] = __builtin_amdgcn_mfma_f32_16x16x32_bf16(alo, bh.s, accR[ct], 0, 0, 0);
      accR[ct] = __builtin_amdgcn_mfma_f32_16x16x32_bf16(ahi, bl.s, accR[ct], 0, 0, 0);
      accR[ct] = __builtin_amdgcn_mfma_f32_16x16x32_bf16(ahi, bh.s, accR[ct], 0, 0, 0);
    }
  }
  gemm_epilogue(sb[0], sb[1], accL, accR, biasL, biasR, CL, CR, N, M, c0g, blockIdx.y * 64);
}

// ---- dual MFMA GEMM with INLINE GraphNorm+ReLU on the A operand ----
template <int K, int M>
__global__ __launch_bounds__(256) void gemm_norm_dual(
    const unsigned short* __restrict__ A, const int* __restrict__ batch,
    const float* __restrict__ sc, const float* __restrict__ sh,
    const uint4* __restrict__ WpkL, const uint4* __restrict__ WpkR,
    const float* __restrict__ biasL, const float* __restrict__ biasR,
    unsigned short* __restrict__ CL, unsigned short* __restrict__ CR, int N) {
  constexpr int nk = K >> 5;
  __shared__ unsigned short sb[2][64 * 72];
  int wv = threadIdx.x >> 6, lane = threadIdx.x & 63;
  int r0 = blockIdx.y * 64 + wv * 16;
  int c0g = blockIdx.x << 2;
  int row = r0 + (lane & 15);
  int kq = (lane >> 4) << 3;
  bool rok = row < N;
  const unsigned short* arow = A + (size_t)row * K;
  int gF = rok ? batch[row] * K : 0;
  f32x4 accL[4], accR[4];
#pragma unroll
  for (int i = 0; i < 4; ++i) { accL[i] = (f32x4){0,0,0,0}; accR[i] = (f32x4){0,0,0,0}; }
#pragma unroll 2
  for (int kc = 0; kc < nk; ++kc) {
    short8 a;
    if (rok) {
      int kf = (kc << 5) + kq;
      uint4 araw = *(const uint4*)(arow + kf);
      float4 s0 = *(const float4*)(sc + gF + kf);
      float4 s1 = *(const float4*)(sc + gF + kf + 4);
      float4 h0 = *(const float4*)(sh + gF + kf);
      float4 h1 = *(const float4*)(sh + gF + kf + 4);
      h2 p0 = u2h2(araw.x), p1 = u2h2(araw.y), p2 = u2h2(araw.z), p3 = u2h2(araw.w);
      float y0 = fmaxf(fmaf((float)p0.x, s0.x, h0.x), 0.f);
      float y1 = fmaxf(fmaf((float)p0.y, s0.y, h0.y), 0.f);
      float y2 = fmaxf(fmaf((float)p1.x, s0.z, h0.z), 0.f);
      float y3 = fmaxf(fmaf((float)p1.y, s0.w, h0.w), 0.f);
      float y4 = fmaxf(fmaf((float)p2.x, s1.x, h1.x), 0.f);
      float y5 = fmaxf(fmaf((float)p2.y, s1.y, h1.y), 0.f);
      float y6 = fmaxf(fmaf((float)p3.x, s1.z, h1.z), 0.f);
      float y7 = fmaxf(fmaf((float)p3.y, s1.w, h1.w), 0.f);
      a[0] = (short)f2bf_rne(y0); a[1] = (short)f2bf_rne(y1);
      a[2] = (short)f2bf_rne(y2); a[3] = (short)f2bf_rne(y3);
      a[4] = (short)f2bf_rne(y4); a[5] = (short)f2bf_rne(y5);
      a[6] = (short)f2bf_rne(y6); a[7] = (short)f2bf_rne(y7);
    } else {
#pragma unroll
      for (int j = 0; j < 8; ++j) a[j] = 0;
    }
#pragma unroll
    for (int ct = 0; ct < 4; ++ct) {
      size_t fo = (((size_t)(c0g + ct) * nk + kc) * 64 + lane) * 2;
      U16 bh, bl;
      bh.u = WpkL[fo]; bl.u = WpkL[fo + 1];
      accL[ct] = __builtin_amdgcn_mfma_f32_16x16x32_bf16(a, bl.s, accL[ct], 0, 0, 0);
      accL[ct] = __builtin_amdgcn_mfma_f32_16x16x32_bf16(a, bh.s, accL[ct], 0, 0, 0);
      bh.u = WpkR[fo]; bl.u = WpkR[fo + 1];
      accR[ct] = __builtin_amdgcn_mfma_f32_16x16x32_bf16(a, bl.s, accR[ct], 0, 0, 0);
      accR[ct] = __builtin_amdgcn_mfma_f32_16x16x32_bf16(a, bh.s, accR[ct], 0, 0, 0);
    }
  }
  gemm_epilogue(sb[0], sb[1], accL, accR, biasL, biasR, CL, CR, N, M, c0g, blockIdx.y * 64);
}

// ---------------- per-VEC edge ops for gat_fused ---------------------------
template <int VEC> struct EO;

template <> struct EO<4> {
  using R = uint2;
  h2 xr0, xr1, at0, at1, sl;
  __device__ void init(const unsigned short* xrp, const float* ap) {
    uint2 rr = *(const uint2*)xrp;
    xr0 = u2h2(rr.x); xr1 = u2h2(rr.y);
    float4 a = *(const float4*)ap;
    at0 = (h2){(_Float16)a.x, (_Float16)a.y};
    at1 = (h2){(_Float16)a.z, (_Float16)a.w};
    sl = (h2){(_Float16)NEG_SLOPE, (_Float16)NEG_SLOPE};
  }
  static __device__ R ld(const unsigned short* base, unsigned off) {
    return *(const uint2*)(base + off);
  }
  __device__ float score(R r) const {
    h2 t0 = u2h2(r.x) + xr0;
    h2 t1 = u2h2(r.y) + xr1;
    t0 = __builtin_elementwise_max(t0, t0 * sl);
    t1 = __builtin_elementwise_max(t1, t1 * sl);
    return fdot2h(t0, at0, fdot2h(t1, at1, 0.f));
  }
  static __device__ void accum(R r, float p, float* o) {
    h2 x0 = u2h2(r.x), x1 = u2h2(r.y);
    o[0] = fmaf(p, (float)x0.x, o[0]);
    o[1] = fmaf(p, (float)x0.y, o[1]);
    o[2] = fmaf(p, (float)x1.x, o[2]);
    o[3] = fmaf(p, (float)x1.y, o[3]);
  }
};

template <> struct EO<2> {
  using R = unsigned;
  h2 xr0, at0, sl;
  __device__ void init(const unsigned short* xrp, const float* ap) {
    xr0 = u2h2(*(const unsigned*)xrp);
    float2 a = *(const float2*)ap;
    at0 = (h2){(_Float16)a.x, (_Float16)a.y};
    sl = (h2){(_Float16)NEG_SLOPE, (_Float16)NEG_SLOPE};
  }
  static __device__ R ld(const unsigned short* base, unsigned off) {
    return *(const unsigned*)(base + off);
  }
  __device__ float score(R r) const {
    h2 t0 = u2h2(r) + xr0;
    t0 = __builtin_elementwise_max(t0, t0 * sl);
    return fdot2h(t0, at0, 0.f);
  }
  static __device__ void accum(R r, float p, float* o) {
    h2 x0 = u2h2(r);
    o[0] = fmaf(p, (float)x0.x, o[0]);
    o[1] = fmaf(p, (float)x0.y, o[1]);
  }
};

template <> struct EO<1> {
  using R = unsigned short;
  float xrf, atf;
  __device__ void init(const unsigned short* xrp, const float* ap) {
    xrf = h2f(*xrp);
    atf = *ap;
  }
  static __device__ R ld(const unsigned short* base, unsigned off) {
    return base[off];
  }
  __device__ float score(R r) const {
    float t = h2f(r) + xrf;
    float lk = fmaxf(t, NEG_SLOPE * t);
    return lk * atf;
  }
  static __device__ void accum(R r, float p, float* o) {
    o[0] = fmaf(p, h2f(r), o[0]);
  }
};

// C-edge unconditional chunk (32-bit offsets: max 50000*256 << 2^32)
template <int VEC, int C>
__device__ inline void gat_chunk(const unsigned short* __restrict__ xl,
                                 const int* __restrict__ csr_src, int j, int f0,
                                 const EO<VEC>& eo, float& lrun, float* o) {
  constexpr int HD = VEC * 64;
  typename EO<VEC>::R r[C];
#pragma unroll
  for (int c = 0; c < C; ++c)
    r[c] = EO<VEC>::ld(xl, (unsigned)csr_src[j + c] * HD + f0);
  float sc[C];
#pragma unroll
  for (int c = 0; c < C; ++c) sc[c] = eo.score(r[c]);
#pragma unroll
  for (int msk = 1; msk <= 8; msk <<= 1)
#pragma unroll
    for (int c = 0; c < C; ++c) sc[c] += __shfl_xor(sc[c], msk, 64);
  float p[C];
#pragma unroll
  for (int c = 0; c < C; ++c) p[c] = __expf(sc[c]);
#pragma unroll
  for (int c = 0; c < C; ++c) lrun += p[c];
#pragma unroll
  for (int c = 0; c < C; ++c) EO<VEC>::accum(r[c], p[c], o);
}

// ---------------- fused GATv2 edge pass: wave per node ----------------------
// Softmax without max subtraction (denom >= exp(smax) => ref's +1e-16 vacuous;
// scores O(10), fp32 exp overflow-safe). Zeroes gsum/gsqs for next stats pass.
template <int VEC, bool MEANH, bool OUT16>
__global__ __launch_bounds__(256) void gat_fused(
    const unsigned short* __restrict__ xl, const unsigned short* __restrict__ xr,
    const float* __restrict__ att, const int* __restrict__ csr_src,
    const int* __restrict__ offp, const float* __restrict__ bias,
    void* __restrict__ outv, float* __restrict__ gsz, float* __restrict__ gqz,
    int n) {
  constexpr int HD = VEC * 64;
  {
    int zt = blockIdx.x * 256 + threadIdx.x;
    if (zt < 32 * 256) { gsz[zt] = 0.f; gqz[zt] = 0.f; }
  }
  int wave = (int)((blockIdx.x * (size_t)blockDim.x + threadIdx.x) >> 6);
  int lane = threadIdx.x & 63;
  if (wave >= n) return;
  const int f0 = lane * VEC;

  EO<VEC> eo;
  eo.init(xr + (size_t)wave * HD + f0, att + f0);

  float lrun = 0.f;
  float o[VEC];
#pragma unroll
  for (int v = 0; v < VEC; ++v) o[v] = 0.f;

  int beg = __builtin_amdgcn_readfirstlane(offp[wave]);
  int end = __builtin_amdgcn_readfirstlane(offp[wave + 1]);  // deg >= 1 (self-loop)
  int j = beg;
  for (; j + 8 <= end; j += 8) gat_chunk<VEC, 8>(xl, csr_src, j, f0, eo, lrun, o);
  if (j + 4 <= end) { gat_chunk<VEC, 4>(xl, csr_src, j, f0, eo, lrun, o); j += 4; }
  for (; j < end; ++j) gat_chunk<VEC, 1>(xl, csr_src, j, f0, eo, lrun, o);

  float invl = 1.f / (lrun + 1e-16f);
  if (!MEANH) {
    if (OUT16) {
      unsigned short* out = (unsigned short*)outv;
#pragma unroll
      for (int v = 0; v < VEC; ++v)
        out[(size_t)wave * HD + f0 + v] = f2h_bits(o[v] * invl + bias[f0 + v]);
    } else {
      float* out = (float*)outv;
#pragma unroll
      for (int v = 0; v < VEC; ++v)
        out[(size_t)wave * HD + f0 + v] = o[v] * invl + bias[f0 + v];
    }
  } else {
    float val = o[0] * invl;
    val += __shfl_xor(val, 16, 64);
    val += __shfl_xor(val, 32, 64);
    val *= 0.25f;
    if (lane < 16) ((float*)outv)[(size_t)wave * 16 + lane] = val + bias[lane];
  }
}

// ---------------- GraphNorm stats + last-block fold into sc/sh --------------
// y = v*sc + sh (relu at consumer). Last block (device-scope counter) reads
// the atomically-accumulated sums and computes sc/sh -- one dispatch.
template <int F, bool H16>
__global__ void gn_statsfin(const void* __restrict__ xv, const int* __restrict__ batch,
                            float* __restrict__ gsum, float* __restrict__ gsqs,
                            const int* __restrict__ cnt,
                            const float* __restrict__ gw, const float* __restrict__ gb,
                            const float* __restrict__ ga,
                            float* __restrict__ sc, float* __restrict__ sh,
                            int* __restrict__ ctr, int n) {
  constexpr int ROWS = 256 / F;
  __shared__ int last;
  int f = threadIdx.x % F;
  int r = threadIdx.x / F;
  int n0 = blockIdx.x * 128;
  float s = 0.f, q = 0.f;
  int curg = -1;
  for (int i = r; i < 128; i += ROWS) {
    int nn = n0 + i;
    if (nn >= n) break;
    int g = batch[nn];
    float v = H16 ? h2f(((const unsigned short*)xv)[(size_t)nn * F + f])
                  : ((const float*)xv)[(size_t)nn * F + f];
    if (g != curg) {
      if (curg >= 0) { atomicAdd(&gsum[curg * F + f], s); atomicAdd(&gsqs[curg * F + f], q); }
      curg = g; s = 0.f; q = 0.f;
    }
    s += v; q += v * v;
  }
  if (curg >= 0) { atomicAdd(&gsum[curg * F + f], s); atomicAdd(&gsqs[curg * F + f], q); }
  __threadfence();
  if (threadIdx.x == 0) last = (atomicAdd(ctr, 1) == (int)gridDim.x - 1);
  __syncthreads();
  if (last) {
    __threadfence();
    for (int idx = threadIdx.x; idx < 32 * F; idx += 256) {
      int g = idx / F, ff = idx - g * F;
      float c = fmaxf((float)cnt[g], 1.f);
      float a = ga[ff];
      float mu = gsum[idx] / c;
      float var = fmaxf(gsqs[idx] / c - (2.f * a - a * a) * mu * mu, 0.f);
      float rstd = rsqrtf(var + 1e-5f);
      float w = gw[ff] * rstd;
      sc[idx] = w;
      sh[idx] = gb[ff] - w * a * mu;
    }
  }
}

// ---------------- L3 norm + pool + last-block final linear ------------------
__global__ void norm_pool_fin(const float* __restrict__ x, const int* __restrict__ batch,
                              const float* __restrict__ sc, const float* __restrict__ sh,
                              float* __restrict__ pooled, const int* __restrict__ cnt,
                              const float* __restrict__ linW, const float* __restrict__ linB,
                              float* __restrict__ out, int* __restrict__ ctr, int n) {
  __shared__ int last;
  __shared__ float feat[32 * 16];
  int f = threadIdx.x & 15;
  int r = threadIdx.x >> 4;
  int n0 = blockIdx.x * 128;
  float s = 0.f;
  int curg = -1;
  float scv = 0.f, shv = 0.f;
  for (int i = r; i < 128; i += 16) {
    int nn = n0 + i;
    if (nn >= n) break;
    int g = batch[nn];
    if (g != curg) {
      if (curg >= 0) atomicAdd(&pooled[curg * 16 + f], s);
      curg = g; s = 0.f;
      scv = sc[g * 16 + f];
      shv = sh[g * 16 + f];
    }
    float v = x[(size_t)nn * 16 + f];
    s += fmaxf(fmaf(v, scv, shv), 0.f);
  }
  if (curg >= 0) atomicAdd(&pooled[curg * 16 + f], s);
  __threadfence();
  if (threadIdx.x == 0) last = (atomicAdd(ctr, 1) == (int)gridDim.x - 1);
  __syncthreads();
  if (last) {
    __threadfence();
    int tid = threadIdx.x;
    for (int t = tid; t < 512; t += 256) {
      int g = t >> 4;
      float c = fmaxf((float)cnt[g], 1.f);
      float v = pooled[t] / c;
      feat[t] = v;
      out[128 + t] = v;  // features [32,16]
    }
    __syncthreads();
    if (tid < 128) {
      int g = tid >> 2, c = tid & 3;
      float sv = linB[c];
#pragma unroll
      for (int k = 0; k < 16; ++k) sv += feat[g * 16 + k] * linW[k * 4 + c];
      out[g * 4 + c] = sv;  // logits [32,4]
    }
  }
}

// ---------------------------------------------------------------------------
extern "C" void kernel_launch(void* const* d_in, const int* in_sizes, int n_in,
                              void* d_out, int out_size, void* d_ws, size_t ws_size,
                              hipStream_t stream) {
  const float* x     = (const float*)d_in[0];
  const int*   ei    = (const int*)d_in[1];
  const int*   batch = (const int*)d_in[2];
  const float* Wl1 = (const float*)d_in[3];
  const float* bl1 = (const float*)d_in[4];
  const float* Wr1 = (const float*)d_in[5];
  const float* br1 = (const float*)d_in[6];
  const float* att1 = (const float*)d_in[7];
  const float* bias1 = (const float*)d_in[8];
  const float* gw1 = (const float*)d_in[9];
  const float* gb1 = (const float*)d_in[10];
  const float* ga1 = (const float*)d_in[11];
  const float* Wl2 = (const float*)d_in[12];
  const float* bl2 = (const float*)d_in[13];
  const float* Wr2 = (const float*)d_in[14];
  const float* br2 = (const float*)d_in[15];
  const float* att2 = (const float*)d_in[16];
  const float* bias2 = (const float*)d_in[17];
  const float* gw2 = (const float*)d_in[18];
  const float* gb2 = (const float*)d_in[19];
  const float* ga2 = (const float*)d_in[20];
  const float* Wl3 = (const float*)d_in[21];
  const float* bl3 = (const float*)d_in[22];
  const float* Wr3 = (const float*)d_in[23];
  const float* br3 = (const float*)d_in[24];
  const float* att3 = (const float*)d_in[25];
  const float* bias3 = (const float*)d_in[26];
  const float* gw3 = (const float*)d_in[27];
  const float* gb3 = (const float*)d_in[28];
  const float* ga3 = (const float*)d_in[29];
  const float* linW = (const float*)d_in[30];
  const float* linB = (const float*)d_in[31];
  float* out = (float*)d_out;

  const int N  = in_sizes[2];      // 50000
  const int E  = in_sizes[1] / 2;  // 800000
  const int ET = E + N;            // 850000

  // workspace carve-up
  char* w = (char*)d_ws;
  float* P = (float*)w;             w += (size_t)N * 256 * 4;  // gat out (fp32 L3 / fp16 L1-2)
  unsigned short* Ph = (unsigned short*)P;
  unsigned short* Qb = (unsigned short*)w; w += (size_t)N * 256 * 2;  // xl fp16
  unsigned short* Rb = (unsigned short*)w; w += (size_t)N * 256 * 2;  // xr fp16
  int* csr_src = (int*)w;           w += (size_t)ET * 4;
  int* offp = (int*)w;              w += (size_t)(N + 1) * 4;
  float* scb = (float*)w;           w += 32 * 256 * 4;  // norm scale
  float* shb = (float*)w;           w += 32 * 256 * 4;  // norm shift
  // ---- contiguous zero-init region ----
  char* z0 = w;
  int* deg  = (int*)w;              w += (size_t)N * 4;
  int* cur  = (int*)w;              w += (size_t)N * 4;
  int* cnt  = (int*)w;              w += 32 * 4;
  int* ctrs = (int*)w;              w += 4 * 4;          // last-block counters
  float* pooled = (float*)w;        w += 512 * 4;
  float* gsum  = (float*)w;         w += 32 * 256 * 4;
  float* gsqs  = (float*)w;         w += 32 * 256 * 4;
  size_t zbytes = (size_t)(w - z0);
  // packed weights (16B aligned)
  uintptr_t wal = ((uintptr_t)w + 15) & ~(uintptr_t)15;
  uint4* wpk1l = (uint4*)wal;
  uint4* wpk1r = wpk1l + 8192;
  uint4* wpk2l = wpk1r + 8192;
  uint4* wpk2r = wpk2l + 8192;
  uint4* wpk3l = wpk2r + 8192;
  uint4* wpk3r = wpk3l + 2048;

  (void)hipMemsetAsync(z0, 0, zbytes, stream);

  int HB = (ET + 255) / 256;
  prep_hist<<<HB + 768, 256, 0, stream>>>(
      ei, batch, deg, cnt, E, N, HB,
      Wl1, Wr1, Wl2, Wr2, Wl3, Wr3,
      (unsigned short*)wpk1l, (unsigned short*)wpk1r,
      (unsigned short*)wpk2l, (unsigned short*)wpk2r,
      (unsigned short*)wpk3l, (unsigned short*)wpk3r);

  int nb = (N + 1023) / 1024;
  scan_all<<<nb, 1024, 0, stream>>>(deg, offp, N);
  scatter_edges<<<(ET + 255) / 256, 256, 0, stream>>>(ei, offp, cur, csr_src, E, N);

  int gry = (N + 63) / 64;
  int gsn = (N + 127) / 128;
  // ---- Layer 1: 128 -> 4x64 concat (HD=256) ----
  gemm_f32a_dual<128, 256><<<dim3(4, gry), 256, 0, stream>>>(x, wpk1l, wpk1r, bl1, br1, Qb, Rb, N);
  gat_fused<4, false, true><<<(N + 3) / 4, 256, 0, stream>>>(Qb, Rb, att1, csr_src, offp, bias1, Ph, gsum, gsqs, N);
  gn_statsfin<256, true><<<gsn, 256, 0, stream>>>(Ph, batch, gsum, gsqs, cnt, gw1, gb1, ga1, scb, shb, &ctrs[0], N);
  // ---- Layer 2: 256 -> 4x32 concat (HD=128); norm of L1 fused into A-load --
  gemm_norm_dual<256, 128><<<dim3(2, gry), 256, 0, stream>>>(Ph, batch, scb, shb, wpk2l, wpk2r, bl2, br2, Qb, Rb, N);
  gat_fused<2, false, true><<<(N + 3) / 4, 256, 0, stream>>>(Qb, Rb, att2, csr_src, offp, bias2, Ph, gsum, gsqs, N);
  gn_statsfin<128, true><<<gsn, 256, 0, stream>>>(Ph, batch, gsum, gsqs, cnt, gw2, gb2, ga2, scb, shb, &ctrs[1], N);
  // ---- Layer 3: 128 -> 4x16 mean heads (HD=64, out 16) ----
  gemm_norm_dual<128, 64><<<dim3(1, gry), 256, 0, stream>>>(Ph, batch, scb, shb, wpk3l, wpk3r, bl3, br3, Qb, Rb, N);
  gat_fused<1, true, false><<<(N + 3) / 4, 256, 0, stream>>>(Qb, Rb, att3, csr_src, offp, bias3, P, gsum, gsqs, N);
  gn_statsfin<16, false><<<gsn, 256, 0, stream>>>(P, batch, gsum, gsqs, cnt, gw3, gb3, ga3, scb, shb, &ctrs[2], N);
  norm_pool_fin<<<gsn, 256, 0, stream>>>(P, batch, scb, shb, pooled, cnt, linW, linB, out, &ctrs[3], N);
}

// Round 14
// 602.996 us; speedup vs baseline: 1.1616x; 1.1616x over previous
//
#include <hip/hip_runtime.h>
#include <cstdint>

// ---------------------------------------------------------------------------
// SimpleGAT: 3x (GATv2 -> GraphNorm -> ReLU) -> mean pool -> linear
// N=50000, E=800000 (+N self loops), H=4 heads, D=64/32/16, G=32 graphs
// Round 14: REVERT R13's last-block fence fusions (device-scope
// __threadfence on non-coherent per-XCD L2 => L2 writeback/invalidate per
// block: gn_statsfin 77us at 2% HBM). Keep the fence-free merges:
// prep_hist (wprep+hist) and scan_all (self-prefix scan). R12 otherwise.
// ---------------------------------------------------------------------------

#define NEG_SLOPE 0.2f

typedef __attribute__((ext_vector_type(8))) short short8;
typedef __attribute__((ext_vector_type(4))) float f32x4;
typedef _Float16 h2 __attribute__((ext_vector_type(2)));
union U16 { uint4 u; short8 s; };

__device__ inline unsigned short f2bf_rne(float x) {
  unsigned u = __float_as_uint(x);
  return (unsigned short)((u + 0x7fff + ((u >> 16) & 1)) >> 16);
}
__device__ inline unsigned short f2h_bits(float x) {
  _Float16 h = (_Float16)x;
  return __builtin_bit_cast(unsigned short, h);
}
__device__ inline float h2f(unsigned short h) {
  return (float)__builtin_bit_cast(_Float16, h);
}
__device__ inline h2 u2h2(unsigned u) { return __builtin_bit_cast(h2, u); }

__device__ inline float fdot2h(h2 a, h2 b, float c) {
#if __has_builtin(__builtin_amdgcn_fdot2)
  return __builtin_amdgcn_fdot2(a, b, c, false);
#else
  return c + (float)a.x * (float)b.x + (float)a.y * (float)b.y;
#endif
}

__device__ inline int wave_incl_scan(int v, int lane) {
#pragma unroll
  for (int ofs = 1; ofs < 64; ofs <<= 1) {
    int t = __shfl_up(v, ofs, 64);
    if (lane >= ofs) v += t;
  }
  return v;
}

// ---------------- weight pre-pack body --------------------------------------
__device__ inline void wprep_body(const float* __restrict__ W, unsigned short* __restrict__ pk,
                                  int K, int M, int t) {
  int nk = K >> 5;
  int total = (M >> 4) * nk * 512;
  if (t >= total) return;
  int j = t & 7;
  int l = (t >> 3) & 63;
  int rest = t >> 9;
  int kc = rest % nk;
  int ct = rest / nk;
  int k = (kc << 5) + ((l >> 4) << 3) + j;
  int col = (ct << 4) + (l & 15);
  float w = W[(size_t)k * M + col];
  unsigned u = __float_as_uint(w);
  unsigned short hi = (unsigned short)(u >> 16);
  float hif = __uint_as_float(u & 0xffff0000u);
  unsigned short lo = f2bf_rne(w - hif);
  unsigned short* dst = pk + ((size_t)(ct * nk + kc) * 64 + l) * 16;
  dst[j] = hi;
  dst[j + 8] = lo;
}

// ---- merged: deg/batch hist (blocks < HB) + weight pre-pack (blocks >= HB) --
__global__ void prep_hist(const int* __restrict__ ei, const int* __restrict__ batch,
                          int* __restrict__ deg, int* __restrict__ cnt, int E, int N, int HB,
                          const float* W0, const float* W1, const float* W2,
                          const float* W3, const float* W4, const float* W5,
                          unsigned short* p0, unsigned short* p1, unsigned short* p2,
                          unsigned short* p3, unsigned short* p4, unsigned short* p5) {
  __shared__ int h[32];
  int b = blockIdx.x;
  if (b < HB) {
    if (threadIdx.x < 32) h[threadIdx.x] = 0;
    __syncthreads();
    int i = b * 256 + threadIdx.x;
    int ET = E + N;
    if (i < ET) {
      int d = (i < E) ? ei[E + i] : (i - E);
      atomicAdd(&deg[d], 1);
    }
    if (i < N) atomicAdd(&h[batch[i]], 1);
    __syncthreads();
    if (threadIdx.x < 32 && h[threadIdx.x] > 0) atomicAdd(&cnt[threadIdx.x], h[threadIdx.x]);
  } else {
    int idx = b - HB;
    int m = idx >> 7;                       // matrix id (128 blocks each)
    int t = (idx & 127) * 256 + threadIdx.x;
    switch (m) {
      case 0: wprep_body(W0, p0, 128, 256, t); break;
      case 1: wprep_body(W1, p1, 128, 256, t); break;
      case 2: wprep_body(W2, p2, 256, 128, t); break;
      case 3: wprep_body(W3, p3, 256, 128, t); break;
      case 4: wprep_body(W4, p4, 128, 64, t); break;
      default: wprep_body(W5, p5, 128, 64, t); break;
    }
  }
}

// ---- single-kernel exclusive scan: each block sums its own prefix region ----
__global__ void scan_all(const int* __restrict__ deg, int* __restrict__ off, int n) {
  __shared__ int ws[16];
  __shared__ int red[16];
  int tid = threadIdx.x, lane = tid & 63, wid = tid >> 6;
  int pend = blockIdx.x * 1024;
  int part = 0;
  for (int i = tid; i < pend; i += 1024) part += deg[i];
#pragma unroll
  for (int m = 32; m; m >>= 1) part += __shfl_xor(part, m, 64);
  if (lane == 0) red[wid] = part;
  __syncthreads();
  if (tid == 0) {
    int s = 0;
#pragma unroll
    for (int k = 0; k < 16; ++k) s += red[k];
    red[0] = s;
  }
  __syncthreads();
  int boff = red[0];
  int i = blockIdx.x * 1024 + tid;
  int v = (i < n) ? deg[i] : 0;
  int incl = wave_incl_scan(v, lane);
  if (lane == 63) ws[wid] = incl;
  __syncthreads();
  if (wid == 0) {
    int t = (lane < 16) ? ws[lane] : 0;
    t = wave_incl_scan(t, lane);
    if (lane < 16) ws[lane] = t;
  }
  __syncthreads();
  int wpre = (wid > 0) ? ws[wid - 1] : 0;
  if (i < n) off[i] = boff + wpre + incl - v;
  if (blockIdx.x == gridDim.x - 1 && tid == 0) off[n] = boff + ws[15];
}

__global__ void scatter_edges(const int* __restrict__ ei, const int* __restrict__ off,
                              int* __restrict__ cur, int* __restrict__ csr_src,
                              int E, int N) {
  int i = blockIdx.x * blockDim.x + threadIdx.x;
  int ET = E + N;
  if (i >= ET) return;
  int s, d;
  if (i < E) { s = ei[i]; d = ei[E + i]; } else { s = d = i - E; }
  int pos = off[d] + atomicAdd(&cur[d], 1);
  csr_src[pos] = s;
}

// ---- shared LDS-bounce epilogue: acc tiles -> coalesced fp16 row stores ----
__device__ inline void gemm_epilogue(
    unsigned short* __restrict__ sb0, unsigned short* __restrict__ sb1,
    f32x4* accL, f32x4* accR,
    const float* __restrict__ biasL, const float* __restrict__ biasR,
    unsigned short* __restrict__ CL, unsigned short* __restrict__ CR,
    int N, int M, int c0g, int row0blk) {
  int wv = threadIdx.x >> 6, lane = threadIdx.x & 63;
  int lrow0 = wv * 16 + ((lane >> 4) << 2);
  int lcolb = lane & 15;
#pragma unroll
  for (int ct = 0; ct < 4; ++ct) {
    int lcol = (ct << 4) + lcolb;
    float bvL = biasL[(c0g << 4) + lcol];
    float bvR = biasR[(c0g << 4) + lcol];
#pragma unroll
    for (int r = 0; r < 4; ++r) {
      sb0[(lrow0 + r) * 72 + lcol] = f2h_bits(accL[ct][r] + bvL);
      sb1[(lrow0 + r) * 72 + lcol] = f2h_bits(accR[ct][r] + bvR);
    }
  }
  __syncthreads();
  int tid = threadIdx.x;
#pragma unroll
  for (int pass = 0; pass < 2; ++pass) {
    int row = (tid >> 3) + (pass << 5);
    int gr = row0blk + row;
    if (gr < N) {
      int co = (tid & 7) << 3;
      uint4 vL = *(const uint4*)&sb0[row * 72 + co];
      uint4 vR = *(const uint4*)&sb1[row * 72 + co];
      size_t go = (size_t)gr * M + (c0g << 4) + co;
      *(uint4*)(CL + go) = vL;
      *(uint4*)(CR + go) = vR;
    }
  }
}

// ---------------- dual MFMA GEMM (fp32 A, hi/lo split ONCE, fp16 out x2) ----
template <int K, int M>
__global__ __launch_bounds__(256) void gemm_f32a_dual(
    const float* __restrict__ A,
    const uint4* __restrict__ WpkL, const uint4* __restrict__ WpkR,
    const float* __restrict__ biasL, const float* __restrict__ biasR,
    unsigned short* __restrict__ CL, unsigned short* __restrict__ CR, int N) {
  constexpr int nk = K >> 5;
  __shared__ unsigned short sb[2][64 * 72];
  int wv = threadIdx.x >> 6, lane = threadIdx.x & 63;
  int r0 = blockIdx.y * 64 + wv * 16;
  int c0g = blockIdx.x << 2;
  int row = r0 + (lane & 15);
  int kq = (lane >> 4) << 3;
  bool rok = row < N;
  const float* arow = A + (size_t)row * K;
  f32x4 accL[4], accR[4];
#pragma unroll
  for (int i = 0; i < 4; ++i) { accL[i] = (f32x4){0,0,0,0}; accR[i] = (f32x4){0,0,0,0}; }
#pragma unroll
  for (int kc = 0; kc < nk; ++kc) {
    float av[8];
    if (rok) {
      float4 t0 = *(const float4*)(arow + (kc << 5) + kq);
      float4 t1 = *(const float4*)(arow + (kc << 5) + kq + 4);
      av[0] = t0.x; av[1] = t0.y; av[2] = t0.z; av[3] = t0.w;
      av[4] = t1.x; av[5] = t1.y; av[6] = t1.z; av[7] = t1.w;
    } else {
#pragma unroll
      for (int j = 0; j < 8; ++j) av[j] = 0.f;
    }
    short8 ahi, alo;
#pragma unroll
    for (int j = 0; j < 8; ++j) {
      unsigned u = __float_as_uint(av[j]);
      ahi[j] = (short)(u >> 16);
      float hif = __uint_as_float(u & 0xffff0000u);
      alo[j] = (short)f2bf_rne(av[j] - hif);
    }
#pragma unroll
    for (int ct = 0; ct < 4; ++ct) {
      size_t fo = (((size_t)(c0g + ct) * nk + kc) * 64 + lane) * 2;
      U16 bh, bl;
      bh.u = WpkL[fo]; bl.u = WpkL[fo + 1];
      accL[ct] = __builtin_amdgcn_mfma_f32_16x16x32_bf16(alo, bh.s, accL[ct], 0, 0, 0);
      accL[ct] = __builtin_amdgcn_mfma_f32_16x16x32_bf16(ahi, bl.s, accL[ct], 0, 0, 0);
      accL[ct] = __builtin_amdgcn_mfma_f32_16x16x32_bf16(ahi, bh.s, accL[ct], 0, 0, 0);
      bh.u = WpkR[fo]; bl.u = WpkR[fo + 1];
      accR[ct] = __builtin_amdgcn_mfma_f32_16x16x32_bf16(alo, bh.s, accR[ct], 0, 0, 0);
      accR[ct] = __builtin_amdgcn_mfma_f32_16x16x32_bf16(ahi, bl.s, accR[ct], 0, 0, 0);
      accR[ct] = __builtin_amdgcn_mfma_f32_16x16x32_bf16(ahi, bh.s, accR[ct], 0, 0, 0);
    }
  }
  gemm_epilogue(sb[0], sb[1], accL, accR, biasL, biasR, CL, CR, N, M, c0g, blockIdx.y * 64);
}

// ---- dual MFMA GEMM with INLINE GraphNorm+ReLU on the A operand ----
template <int K, int M>
__global__ __launch_bounds__(256) void gemm_norm_dual(
    const unsigned short* __restrict__ A, const int* __restrict__ batch,
    const float* __restrict__ sc, const float* __restrict__ sh,
    const uint4* __restrict__ WpkL, const uint4* __restrict__ WpkR,
    const float* __restrict__ biasL, const float* __restrict__ biasR,
    unsigned short* __restrict__ CL, unsigned short* __restrict__ CR, int N) {
  constexpr int nk = K >> 5;
  __shared__ unsigned short sb[2][64 * 72];
  int wv = threadIdx.x >> 6, lane = threadIdx.x & 63;
  int r0 = blockIdx.y * 64 + wv * 16;
  int c0g = blockIdx.x << 2;
  int row = r0 + (lane & 15);
  int kq = (lane >> 4) << 3;
  bool rok = row < N;
  const unsigned short* arow = A + (size_t)row * K;
  int gF = rok ? batch[row] * K : 0;
  f32x4 accL[4], accR[4];
#pragma unroll
  for (int i = 0; i < 4; ++i) { accL[i] = (f32x4){0,0,0,0}; accR[i] = (f32x4){0,0,0,0}; }
#pragma unroll 2
  for (int kc = 0; kc < nk; ++kc) {
    short8 a;
    if (rok) {
      int kf = (kc << 5) + kq;
      uint4 araw = *(const uint4*)(arow + kf);
      float4 s0 = *(const float4*)(sc + gF + kf);
      float4 s1 = *(const float4*)(sc + gF + kf + 4);
      float4 h0 = *(const float4*)(sh + gF + kf);
      float4 h1 = *(const float4*)(sh + gF + kf + 4);
      h2 p0 = u2h2(araw.x), p1 = u2h2(araw.y), p2 = u2h2(araw.z), p3 = u2h2(araw.w);
      float y0 = fmaxf(fmaf((float)p0.x, s0.x, h0.x), 0.f);
      float y1 = fmaxf(fmaf((float)p0.y, s0.y, h0.y), 0.f);
      float y2 = fmaxf(fmaf((float)p1.x, s0.z, h0.z), 0.f);
      float y3 = fmaxf(fmaf((float)p1.y, s0.w, h0.w), 0.f);
      float y4 = fmaxf(fmaf((float)p2.x, s1.x, h1.x), 0.f);
      float y5 = fmaxf(fmaf((float)p2.y, s1.y, h1.y), 0.f);
      float y6 = fmaxf(fmaf((float)p3.x, s1.z, h1.z), 0.f);
      float y7 = fmaxf(fmaf((float)p3.y, s1.w, h1.w), 0.f);
      a[0] = (short)f2bf_rne(y0); a[1] = (short)f2bf_rne(y1);
      a[2] = (short)f2bf_rne(y2); a[3] = (short)f2bf_rne(y3);
      a[4] = (short)f2bf_rne(y4); a[5] = (short)f2bf_rne(y5);
      a[6] = (short)f2bf_rne(y6); a[7] = (short)f2bf_rne(y7);
    } else {
#pragma unroll
      for (int j = 0; j < 8; ++j) a[j] = 0;
    }
#pragma unroll
    for (int ct = 0; ct < 4; ++ct) {
      size_t fo = (((size_t)(c0g + ct) * nk + kc) * 64 + lane) * 2;
      U16 bh, bl;
      bh.u = WpkL[fo]; bl.u = WpkL[fo + 1];
      accL[ct] = __builtin_amdgcn_mfma_f32_16x16x32_bf16(a, bl.s, accL[ct], 0, 0, 0);
      accL[ct] = __builtin_amdgcn_mfma_f32_16x16x32_bf16(a, bh.s, accL[ct], 0, 0, 0);
      bh.u = WpkR[fo]; bl.u = WpkR[fo + 1];
      accR[ct] = __builtin_amdgcn_mfma_f32_16x16x32_bf16(a, bl.s, accR[ct], 0, 0, 0);
      accR[ct] = __builtin_amdgcn_mfma_f32_16x16x32_bf16(a, bh.s, accR[ct], 0, 0, 0);
    }
  }
  gemm_epilogue(sb[0], sb[1], accL, accR, biasL, biasR, CL, CR, N, M, c0g, blockIdx.y * 64);
}

// ---------------- per-VEC edge ops for gat_fused ---------------------------
template <int VEC> struct EO;

template <> struct EO<4> {
  using R = uint2;
  h2 xr0, xr1, at0, at1, sl;
  __device__ void init(const unsigned short* xrp, const float* ap) {
    uint2 rr = *(const uint2*)xrp;
    xr0 = u2h2(rr.x); xr1 = u2h2(rr.y);
    float4 a = *(const float4*)ap;
    at0 = (h2){(_Float16)a.x, (_Float16)a.y};
    at1 = (h2){(_Float16)a.z, (_Float16)a.w};
    sl = (h2){(_Float16)NEG_SLOPE, (_Float16)NEG_SLOPE};
  }
  static __device__ R ld(const unsigned short* base, unsigned off) {
    return *(const uint2*)(base + off);
  }
  __device__ float score(R r) const {
    h2 t0 = u2h2(r.x) + xr0;
    h2 t1 = u2h2(r.y) + xr1;
    t0 = __builtin_elementwise_max(t0, t0 * sl);
    t1 = __builtin_elementwise_max(t1, t1 * sl);
    return fdot2h(t0, at0, fdot2h(t1, at1, 0.f));
  }
  static __device__ void accum(R r, float p, float* o) {
    h2 x0 = u2h2(r.x), x1 = u2h2(r.y);
    o[0] = fmaf(p, (float)x0.x, o[0]);
    o[1] = fmaf(p, (float)x0.y, o[1]);
    o[2] = fmaf(p, (float)x1.x, o[2]);
    o[3] = fmaf(p, (float)x1.y, o[3]);
  }
};

template <> struct EO<2> {
  using R = unsigned;
  h2 xr0, at0, sl;
  __device__ void init(const unsigned short* xrp, const float* ap) {
    xr0 = u2h2(*(const unsigned*)xrp);
    float2 a = *(const float2*)ap;
    at0 = (h2){(_Float16)a.x, (_Float16)a.y};
    sl = (h2){(_Float16)NEG_SLOPE, (_Float16)NEG_SLOPE};
  }
  static __device__ R ld(const unsigned short* base, unsigned off) {
    return *(const unsigned*)(base + off);
  }
  __device__ float score(R r) const {
    h2 t0 = u2h2(r) + xr0;
    t0 = __builtin_elementwise_max(t0, t0 * sl);
    return fdot2h(t0, at0, 0.f);
  }
  static __device__ void accum(R r, float p, float* o) {
    h2 x0 = u2h2(r);
    o[0] = fmaf(p, (float)x0.x, o[0]);
    o[1] = fmaf(p, (float)x0.y, o[1]);
  }
};

template <> struct EO<1> {
  using R = unsigned short;
  float xrf, atf;
  __device__ void init(const unsigned short* xrp, const float* ap) {
    xrf = h2f(*xrp);
    atf = *ap;
  }
  static __device__ R ld(const unsigned short* base, unsigned off) {
    return base[off];
  }
  __device__ float score(R r) const {
    float t = h2f(r) + xrf;
    float lk = fmaxf(t, NEG_SLOPE * t);
    return lk * atf;
  }
  static __device__ void accum(R r, float p, float* o) {
    o[0] = fmaf(p, h2f(r), o[0]);
  }
};

// C-edge unconditional chunk (32-bit offsets: max 50000*256 << 2^32)
template <int VEC, int C>
__device__ inline void gat_chunk(const unsigned short* __restrict__ xl,
                                 const int* __restrict__ csr_src, int j, int f0,
                                 const EO<VEC>& eo, float& lrun, float* o) {
  constexpr int HD = VEC * 64;
  typename EO<VEC>::R r[C];
#pragma unroll
  for (int c = 0; c < C; ++c)
    r[c] = EO<VEC>::ld(xl, (unsigned)csr_src[j + c] * HD + f0);
  float sc[C];
#pragma unroll
  for (int c = 0; c < C; ++c) sc[c] = eo.score(r[c]);
#pragma unroll
  for (int msk = 1; msk <= 8; msk <<= 1)
#pragma unroll
    for (int c = 0; c < C; ++c) sc[c] += __shfl_xor(sc[c], msk, 64);
  float p[C];
#pragma unroll
  for (int c = 0; c < C; ++c) p[c] = __expf(sc[c]);
#pragma unroll
  for (int c = 0; c < C; ++c) lrun += p[c];
#pragma unroll
  for (int c = 0; c < C; ++c) EO<VEC>::accum(r[c], p[c], o);
}

// ---------------- fused GATv2 edge pass: wave per node ----------------------
// Softmax without max subtraction (denom >= exp(smax) => ref's +1e-16 vacuous;
// scores O(10), fp32 exp overflow-safe). Zeroes gsum/gsqs for next stats pass.
template <int VEC, bool MEANH, bool OUT16>
__global__ __launch_bounds__(256) void gat_fused(
    const unsigned short* __restrict__ xl, const unsigned short* __restrict__ xr,
    const float* __restrict__ att, const int* __restrict__ csr_src,
    const int* __restrict__ offp, const float* __restrict__ bias,
    void* __restrict__ outv, float* __restrict__ gsz, float* __restrict__ gqz,
    int n) {
  constexpr int HD = VEC * 64;
  {
    int zt = blockIdx.x * 256 + threadIdx.x;
    if (zt < 32 * 256) { gsz[zt] = 0.f; gqz[zt] = 0.f; }
  }
  int wave = (int)((blockIdx.x * (size_t)blockDim.x + threadIdx.x) >> 6);
  int lane = threadIdx.x & 63;
  if (wave >= n) return;
  const int f0 = lane * VEC;

  EO<VEC> eo;
  eo.init(xr + (size_t)wave * HD + f0, att + f0);

  float lrun = 0.f;
  float o[VEC];
#pragma unroll
  for (int v = 0; v < VEC; ++v) o[v] = 0.f;

  int beg = __builtin_amdgcn_readfirstlane(offp[wave]);
  int end = __builtin_amdgcn_readfirstlane(offp[wave + 1]);  // deg >= 1 (self-loop)
  int j = beg;
  for (; j + 8 <= end; j += 8) gat_chunk<VEC, 8>(xl, csr_src, j, f0, eo, lrun, o);
  if (j + 4 <= end) { gat_chunk<VEC, 4>(xl, csr_src, j, f0, eo, lrun, o); j += 4; }
  for (; j < end; ++j) gat_chunk<VEC, 1>(xl, csr_src, j, f0, eo, lrun, o);

  float invl = 1.f / (lrun + 1e-16f);
  if (!MEANH) {
    if (OUT16) {
      unsigned short* out = (unsigned short*)outv;
#pragma unroll
      for (int v = 0; v < VEC; ++v)
        out[(size_t)wave * HD + f0 + v] = f2h_bits(o[v] * invl + bias[f0 + v]);
    } else {
      float* out = (float*)outv;
#pragma unroll
      for (int v = 0; v < VEC; ++v)
        out[(size_t)wave * HD + f0 + v] = o[v] * invl + bias[f0 + v];
    }
  } else {
    float val = o[0] * invl;
    val += __shfl_xor(val, 16, 64);
    val += __shfl_xor(val, 32, 64);
    val *= 0.25f;
    if (lane < 16) ((float*)outv)[(size_t)wave * 16 + lane] = val + bias[lane];
  }
}

// ---------------- GraphNorm stats ----------------
template <int F>
__global__ void gn_stats_h(const unsigned short* __restrict__ x, const int* __restrict__ batch,
                           float* __restrict__ gsum, float* __restrict__ gsqs, int n) {
  constexpr int ROWS = 256 / F;
  int f = threadIdx.x % F;
  int r = threadIdx.x / F;
  int n0 = blockIdx.x * 128;
  float s = 0.f, q = 0.f;
  int curg = -1;
  for (int i = r; i < 128; i += ROWS) {
    int nn = n0 + i;
    if (nn >= n) break;
    int g = batch[nn];
    float v = h2f(x[(size_t)nn * F + f]);
    if (g != curg) {
      if (curg >= 0) { atomicAdd(&gsum[curg * F + f], s); atomicAdd(&gsqs[curg * F + f], q); }
      curg = g; s = 0.f; q = 0.f;
    }
    s += v; q += v * v;
  }
  if (curg >= 0) { atomicAdd(&gsum[curg * F + f], s); atomicAdd(&gsqs[curg * F + f], q); }
}

template <int F>
__global__ void gn_stats(const float* __restrict__ x, const int* __restrict__ batch,
                         float* __restrict__ gsum, float* __restrict__ gsqs, int n) {
  constexpr int ROWS = 256 / F;
  int f = threadIdx.x % F;
  int r = threadIdx.x / F;
  int n0 = blockIdx.x * 128;
  float s = 0.f, q = 0.f;
  int curg = -1;
  for (int i = r; i < 128; i += ROWS) {
    int nn = n0 + i;
    if (nn >= n) break;
    int g = batch[nn];
    float v = x[(size_t)nn * F + f];
    if (g != curg) {
      if (curg >= 0) { atomicAdd(&gsum[curg * F + f], s); atomicAdd(&gsqs[curg * F + f], q); }
      curg = g; s = 0.f; q = 0.f;
    }
    s += v; q += v * v;
  }
  if (curg >= 0) { atomicAdd(&gsum[curg * F + f], s); atomicAdd(&gsqs[curg * F + f], q); }
}

// fold stats into per-(g,f) scale/shift: y = v*sc + sh (then relu at consumer)
__global__ void gn_final(const float* __restrict__ gsum, const float* __restrict__ gsqs,
                         const int* __restrict__ cnt, const float* __restrict__ gw,
                         const float* __restrict__ gb, const float* __restrict__ ga,
                         float* __restrict__ sc, float* __restrict__ sh, int F) {
  int idx = blockIdx.x * blockDim.x + threadIdx.x;
  if (idx >= 32 * F) return;
  int g = idx / F, f = idx - g * F;
  float c = fmaxf((float)cnt[g], 1.f);
  float a = ga[f];
  float mu = gsum[idx] / c;
  float var = fmaxf(gsqs[idx] / c - (2.f * a - a * a) * mu * mu, 0.f);
  float rstd = rsqrtf(var + 1e-5f);
  float w = gw[f] * rstd;
  sc[idx] = w;
  sh[idx] = gb[f] - w * a * mu;
}

// ---------------- L3 norm + pool fused (no write-back of P) ----------------
__global__ void norm_pool(const float* __restrict__ x, const int* __restrict__ batch,
                          const float* __restrict__ sc, const float* __restrict__ sh,
                          float* __restrict__ pooled, int n) {
  int f = threadIdx.x & 15;
  int r = threadIdx.x >> 4;
  int n0 = blockIdx.x * 128;
  float s = 0.f;
  int curg = -1;
  float scv = 0.f, shv = 0.f;
  for (int i = r; i < 128; i += 16) {
    int nn = n0 + i;
    if (nn >= n) break;
    int g = batch[nn];
    if (g != curg) {
      if (curg >= 0) atomicAdd(&pooled[curg * 16 + f], s);
      curg = g; s = 0.f;
      scv = sc[g * 16 + f];
      shv = sh[g * 16 + f];
    }
    float v = x[(size_t)nn * 16 + f];
    s += fmaxf(fmaf(v, scv, shv), 0.f);
  }
  if (curg >= 0) atomicAdd(&pooled[curg * 16 + f], s);
}

__global__ void finalize(const float* __restrict__ pooled, const int* __restrict__ cnt,
                         const float* __restrict__ linW, const float* __restrict__ linB,
                         float* __restrict__ out) {
  __shared__ float feat[32 * 16];
  int tid = threadIdx.x;  // 512 threads
  {
    int g = tid >> 4;
    float c = fmaxf((float)cnt[g], 1.f);
    float v = pooled[tid] / c;
    feat[tid] = v;
    out[128 + tid] = v;  // features [32,16]
  }
  __syncthreads();
  if (tid < 128) {
    int g = tid >> 2, c = tid & 3;
    float s = linB[c];
#pragma unroll
    for (int k = 0; k < 16; ++k) s += feat[g * 16 + k] * linW[k * 4 + c];
    out[g * 4 + c] = s;  // logits [32,4]
  }
}

// ---------------------------------------------------------------------------
extern "C" void kernel_launch(void* const* d_in, const int* in_sizes, int n_in,
                              void* d_out, int out_size, void* d_ws, size_t ws_size,
                              hipStream_t stream) {
  const float* x     = (const float*)d_in[0];
  const int*   ei    = (const int*)d_in[1];
  const int*   batch = (const int*)d_in[2];
  const float* Wl1 = (const float*)d_in[3];
  const float* bl1 = (const float*)d_in[4];
  const float* Wr1 = (const float*)d_in[5];
  const float* br1 = (const float*)d_in[6];
  const float* att1 = (const float*)d_in[7];
  const float* bias1 = (const float*)d_in[8];
  const float* gw1 = (const float*)d_in[9];
  const float* gb1 = (const float*)d_in[10];
  const float* ga1 = (const float*)d_in[11];
  const float* Wl2 = (const float*)d_in[12];
  const float* bl2 = (const float*)d_in[13];
  const float* Wr2 = (const float*)d_in[14];
  const float* br2 = (const float*)d_in[15];
  const float* att2 = (const float*)d_in[16];
  const float* bias2 = (const float*)d_in[17];
  const float* gw2 = (const float*)d_in[18];
  const float* gb2 = (const float*)d_in[19];
  const float* ga2 = (const float*)d_in[20];
  const float* Wl3 = (const float*)d_in[21];
  const float* bl3 = (const float*)d_in[22];
  const float* Wr3 = (const float*)d_in[23];
  const float* br3 = (const float*)d_in[24];
  const float* att3 = (const float*)d_in[25];
  const float* bias3 = (const float*)d_in[26];
  const float* gw3 = (const float*)d_in[27];
  const float* gb3 = (const float*)d_in[28];
  const float* ga3 = (const float*)d_in[29];
  const float* linW = (const float*)d_in[30];
  const float* linB = (const float*)d_in[31];
  float* out = (float*)d_out;

  const int N  = in_sizes[2];      // 50000
  const int E  = in_sizes[1] / 2;  // 800000
  const int ET = E + N;            // 850000

  // workspace carve-up
  char* w = (char*)d_ws;
  float* P = (float*)w;             w += (size_t)N * 256 * 4;  // gat out (fp32 L3 / fp16 L1-2)
  unsigned short* Ph = (unsigned short*)P;
  unsigned short* Qb = (unsigned short*)w; w += (size_t)N * 256 * 2;  // xl fp16
  unsigned short* Rb = (unsigned short*)w; w += (size_t)N * 256 * 2;  // xr fp16
  int* csr_src = (int*)w;           w += (size_t)ET * 4;
  int* offp = (int*)w;              w += (size_t)(N + 1) * 4;
  float* scb = (float*)w;           w += 32 * 256 * 4;  // norm scale
  float* shb = (float*)w;           w += 32 * 256 * 4;  // norm shift
  // ---- contiguous zero-init region ----
  char* z0 = w;
  int* deg  = (int*)w;              w += (size_t)N * 4;
  int* cur  = (int*)w;              w += (size_t)N * 4;
  int* cnt  = (int*)w;              w += 32 * 4;
  float* pooled = (float*)w;        w += 512 * 4;
  float* gsum  = (float*)w;         w += 32 * 256 * 4;
  float* gsqs  = (float*)w;         w += 32 * 256 * 4;
  size_t zbytes = (size_t)(w - z0);
  // packed weights (16B aligned)
  uintptr_t wal = ((uintptr_t)w + 15) & ~(uintptr_t)15;
  uint4* wpk1l = (uint4*)wal;
  uint4* wpk1r = wpk1l + 8192;
  uint4* wpk2l = wpk1r + 8192;
  uint4* wpk2r = wpk2l + 8192;
  uint4* wpk3l = wpk2r + 8192;
  uint4* wpk3r = wpk3l + 2048;

  (void)hipMemsetAsync(z0, 0, zbytes, stream);

  int HB = (ET + 255) / 256;
  prep_hist<<<HB + 768, 256, 0, stream>>>(
      ei, batch, deg, cnt, E, N, HB,
      Wl1, Wr1, Wl2, Wr2, Wl3, Wr3,
      (unsigned short*)wpk1l, (unsigned short*)wpk1r,
      (unsigned short*)wpk2l, (unsigned short*)wpk2r,
      (unsigned short*)wpk3l, (unsigned short*)wpk3r);

  int nb = (N + 1023) / 1024;
  scan_all<<<nb, 1024, 0, stream>>>(deg, offp, N);
  scatter_edges<<<(ET + 255) / 256, 256, 0, stream>>>(ei, offp, cur, csr_src, E, N);

  int gry = (N + 63) / 64;
  int gsn = (N + 127) / 128;
  // ---- Layer 1: 128 -> 4x64 concat (HD=256) ----
  gemm_f32a_dual<128, 256><<<dim3(4, gry), 256, 0, stream>>>(x, wpk1l, wpk1r, bl1, br1, Qb, Rb, N);
  gat_fused<4, false, true><<<(N + 3) / 4, 256, 0, stream>>>(Qb, Rb, att1, csr_src, offp, bias1, Ph, gsum, gsqs, N);
  gn_stats_h<256><<<gsn, 256, 0, stream>>>(Ph, batch, gsum, gsqs, N);
  gn_final<<<32, 256, 0, stream>>>(gsum, gsqs, cnt, gw1, gb1, ga1, scb, shb, 256);
  // ---- Layer 2: 256 -> 4x32 concat (HD=128); norm of L1 fused into A-load --
  gemm_norm_dual<256, 128><<<dim3(2, gry), 256, 0, stream>>>(Ph, batch, scb, shb, wpk2l, wpk2r, bl2, br2, Qb, Rb, N);
  gat_fused<2, false, true><<<(N + 3) / 4, 256, 0, stream>>>(Qb, Rb, att2, csr_src, offp, bias2, Ph, gsum, gsqs, N);
  gn_stats_h<128><<<gsn, 256, 0, stream>>>(Ph, batch, gsum, gsqs, N);
  gn_final<<<16, 256, 0, stream>>>(gsum, gsqs, cnt, gw2, gb2, ga2, scb, shb, 128);
  // ---- Layer 3: 128 -> 4x16 mean heads (HD=64, out 16) ----
  gemm_norm_dual<128, 64><<<dim3(1, gry), 256, 0, stream>>>(Ph, batch, scb, shb, wpk3l, wpk3r, bl3, br3, Qb, Rb, N);
  gat_fused<1, true, false><<<(N + 3) / 4, 256, 0, stream>>>(Qb, Rb, att3, csr_src, offp, bias3, P, gsum, gsqs, N);
  gn_stats<16><<<gsn, 256, 0, stream>>>(P, batch, gsum, gsqs, N);
  gn_final<<<2, 256, 0, stream>>>(gsum, gsqs, cnt, gw3, gb3, ga3, scb, shb, 16);
  norm_pool<<<gsn, 256, 0, stream>>>(P, batch, scb, shb, pooled, N);
  finalize<<<1, 512, 0, stream>>>(pooled, cnt, linW, linB, out);
}